// Round 15
// baseline (119.020 us; speedup 1.0000x reference)
//
#include <hip/hip_runtime.h>

#define B 128
#define S 512
#define T 64

typedef short bf16x8 __attribute__((ext_vector_type(8)));
typedef float f32x4 __attribute__((ext_vector_type(4)));
typedef _Float16 h2 __attribute__((ext_vector_type(2)));

__device__ __forceinline__ float rdlane(float v, int l) {
    return __int_as_float(__builtin_amdgcn_readlane(__float_as_int(v), l));
}
__device__ __forceinline__ unsigned cvtpk_bf16(float lo, float hi) {
    unsigned r;
    asm("v_cvt_pk_bf16_f32 %0, %1, %2" : "=v"(r) : "v"(lo), "v"(hi));
    return r;
}
__device__ __forceinline__ float fast_exp2(float x) {
    float r;
    asm("v_exp_f32 %0, %1" : "=v"(r) : "v"(x));
    return r;
}
// Inline-asm MFMA with VGPR accumulators (gfx950 unified file): avoids the
// compiler's AGPR allocation + v_accvgpr_read/write bounces seen r9-r14.
__device__ __forceinline__ f32x4 mfma_init(bf16x8 a, bf16x8 b, f32x4 c0) {
    f32x4 d;
    asm volatile("v_mfma_f32_16x16x32_bf16 %0, %1, %2, %3"
                 : "=&v"(d) : "v"(a), "v"(b), "v"(c0));
    return d;
}
__device__ __forceinline__ void mfma_acc(f32x4& c, bf16x8 a, bf16x8 b) {
    asm volatile("v_mfma_f32_16x16x32_bf16 %0, %1, %2, %0"
                 : "+v"(c) : "v"(a), "v"(b));
}
// A/B fragment k-index for mfma_f32_16x16x32_bf16, SPLIT-HALF mapping
// (validated round 6, absmax=0): e=0..3 -> k=4*gq+e ; e=4..7 -> k=16+4*gq+(e-4)
__device__ __forceinline__ int krow(int kt, int gq, int e) {
    return 32 * kt + ((e >> 2) << 4) + 4 * gq + (e & 3);
}

// ============================================================================
// Phase 1, ROUND 15: G=32 chunks (16 steps), 4 waves/block = 4 consecutive
// chunks of one batch. After building Z_g, wave PAIRS combine W = Z_odd *
// Z_even in-block via the relay slabs -> G=16 output for the proven apply.
// MFMA acc forced into VGPRs via inline asm; launch_bounds(256,4) caps the
// unified file at 128 regs/wave -> 16 waves/CU (4 blocks x 34.8KB LDS).
// ============================================================================
__global__ __launch_bounds__(256, 4)
void crf_chunk_comb(const float* __restrict__ features,
                    const float* __restrict__ mask,
                    const float* __restrict__ transitions,
                    unsigned short* __restrict__ Zout,
                    int* __restrict__ Kout)
{
    constexpr int GG = 32, CLT = S / GG;        // 16 steps per chunk
    __shared__ unsigned short relay[4][T * 68]; // per-wave col-major slab
    __shared__ int   kt_sh[4];
    __shared__ float mx_sh[4];

    const int wid  = threadIdx.x >> 6;
    const int lane = threadIdx.x & 63;
    const int b   = blockIdx.x >> 3;            // 8 blocks per batch
    const int q4  = blockIdx.x & 7;
    const int g   = q4 * 4 + wid;
    const int c   = lane & 15;
    const int gq  = lane >> 4;

    // ---- static A = E^T in bf16 fragments: A[i][k] = exp(W[k][i]) ----
    bf16x8 Ef[4][2];
    #pragma unroll
    for (int rt = 0; rt < 4; ++rt)
      #pragma unroll
      for (int kt = 0; kt < 2; ++kt) {
          unsigned dw[4];
          #pragma unroll
          for (int w = 0; w < 4; ++w) {
              int k0 = krow(kt, gq, 2 * w);
              float x0 = __expf(transitions[k0       * T + (c + 16*rt)]);
              float x1 = __expf(transitions[(k0 + 1) * T + (c + 16*rt)]);
              dw[w] = cvtpk_bf16(x0, x1);
          }
          uint4 q; q.x = dw[0]; q.y = dw[1]; q.z = dw[2]; q.w = dw[3];
          Ef[rt][kt] = __builtin_bit_cast(bf16x8, q);
      }

    // ---- Z init = identity, B-fragment layout ----
    bf16x8 Bf[2][4];
    #pragma unroll
    for (int kt = 0; kt < 2; ++kt)
      #pragma unroll
      for (int ct = 0; ct < 4; ++ct)
        #pragma unroll
        for (int e = 0; e < 8; ++e)
            Bf[kt][ct][e] = (krow(kt, gq, e) == 16*ct + c) ? (short)0x3F80
                                                           : (short)0;

    const float* fb = features + (size_t)b * S * T;
    const float* mb = mask + (size_t)b * S;
    const int t0 = g * CLT + 1;
    const int t1 = (g == GG - 1) ? S : (t0 + CLT);

    const f32x4 zero4 = {0.f, 0.f, 0.f, 0.f};

    int ktot = 0;
    float zloc = 1.0f, mxr = 1.0f;

    // emission/mask prefetch depth 1 (step ~1500cy >> L2 latency)
    f32x4 emP[4];
    #pragma unroll
    for (int rt = 0; rt < 4; ++rt)
        emP[rt] = *(const f32x4*)(fb + t0 * T + 16*rt + 4*gq);
    float mP = mb[t0];

    for (int w = 0; w < CLT / 4; ++w) {
        #pragma unroll
        for (int j = 0; j < 4; ++j) {
            const int t = t0 + 4 * w + j;
            const bool act = (t < t1);

            f32x4 emc[4];
            #pragma unroll
            for (int rt = 0; rt < 4; ++rt) emc[rt] = emP[rt];
            float mc = mP;
            {   // prefetch t+1
                int tn = min(t + 1, S - 1);
                #pragma unroll
                for (int rt = 0; rt < 4; ++rt)
                    emP[rt] = *(const f32x4*)(fb + tn * T + 16*rt + 4*gq);
                mP = mb[tn];
            }

            int kc = 0;
            if (j == 0) {   // consume reduce launched in window w-1 (lag-2)
                kc = ((__float_as_int(mxr) >> 23) & 0xFF) - 127;
                kc = kc < -30 ? -30 : (kc > 60 ? 60 : kc);
            }

            if (act && mc != 0.0f) {
                if (j == 0) ktot += kc;
                const float kcf = (j == 0) ? (float)kc : 0.0f;

                f32x4 d4[4];
                #pragma unroll
                for (int rt = 0; rt < 4; ++rt)
                    #pragma unroll
                    for (int r = 0; r < 4; ++r)
                        d4[rt][r] = fast_exp2(fmaf(emc[rt][r], 1.44269504f, -kcf));

                #pragma unroll
                for (int ct = 0; ct < 4; ++ct) {
                    f32x4 Ct[4];
                    #pragma unroll
                    for (int tr = 0; tr < 4; ++tr) {
                        f32x4 z = mfma_init(Ef[tr][0], Bf[0][ct], zero4);
                        mfma_acc(z, Ef[tr][1], Bf[1][ct]);
                        Ct[tr] = z;
                    }
                    asm volatile("s_nop 7\ns_nop 7");   // MFMA->VALU hazard
                    #pragma unroll
                    for (int tr = 0; tr < 4; ++tr) {
                        Ct[tr] *= d4[tr];               // C-side row scale
                        zloc = fmaxf(zloc, fmaxf(fmaxf(Ct[tr][0], Ct[tr][1]),
                                                 fmaxf(Ct[tr][2], Ct[tr][3])));
                    }
                    uint4 q0, q1;
                    q0.x = cvtpk_bf16(Ct[0][0], Ct[0][1]);
                    q0.y = cvtpk_bf16(Ct[0][2], Ct[0][3]);
                    q0.z = cvtpk_bf16(Ct[1][0], Ct[1][1]);
                    q0.w = cvtpk_bf16(Ct[1][2], Ct[1][3]);
                    q1.x = cvtpk_bf16(Ct[2][0], Ct[2][1]);
                    q1.y = cvtpk_bf16(Ct[2][2], Ct[2][3]);
                    q1.z = cvtpk_bf16(Ct[3][0], Ct[3][1]);
                    q1.w = cvtpk_bf16(Ct[3][2], Ct[3][3]);
                    Bf[0][ct] = __builtin_bit_cast(bf16x8, q0);
                    Bf[1][ct] = __builtin_bit_cast(bf16x8, q1);
                }
            }

            if (j == 2) {   // cross-lane reduce, consumed next window
                float mr = zloc;
                #pragma unroll
                for (int o = 32; o > 0; o >>= 1)
                    mr = fmaxf(mr, __shfl_xor(mr, o));
                mxr = mr; zloc = 1.0f;
            }
        }
    }

    // ---- stage own Z col-major into relay[wid]; publish ktot ----
    unsigned short* rl = relay[wid];
    #pragma unroll
    for (int kt = 0; kt < 2; ++kt)
      #pragma unroll
      for (int ct = 0; ct < 4; ++ct) {
          uint4 q = __builtin_bit_cast(uint4, Bf[kt][ct]);
          int col = 16*ct + c;
          uint2 wa; wa.x = q.x; wa.y = q.y;
          uint2 wb; wb.x = q.z; wb.y = q.w;
          *(uint2*)&rl[col * 68 + 32*kt      + 4*gq] = wa;
          *(uint2*)&rl[col * 68 + 32*kt + 16 + 4*gq] = wb;
      }
    if (lane == 0) kt_sh[wid] = ktot;
    __syncthreads();

    // ---- pair combine: W = Z_odd * Z_even  (waves 2p,2p+1 split cols) ----
    const int p    = wid >> 1;
    const int odd  = wid & 1;
    const unsigned short* rlA = relay[2*p + 1];   // A = Z_odd
    const unsigned short* rlB = relay[2*p];       // B = Z_even

    // A-fragments: A[i][k] = Zodd[i][k] = rlA[k*68 + i], i = c+16rt
    bf16x8 Af[4][2];
    #pragma unroll
    for (int rt = 0; rt < 4; ++rt)
      #pragma unroll
      for (int kt = 0; kt < 2; ++kt) {
          unsigned dw[4];
          #pragma unroll
          for (int w = 0; w < 4; ++w) {
              int k0 = krow(kt, gq, 2 * w);
              unsigned lo = rlA[(k0    ) * 68 + (c + 16*rt)];
              unsigned hi = rlA[(k0 + 1) * 68 + (c + 16*rt)];
              dw[w] = lo | (hi << 16);
          }
          uint4 q; q.x = dw[0]; q.y = dw[1]; q.z = dw[2]; q.w = dw[3];
          Af[rt][kt] = __builtin_bit_cast(bf16x8, q);
      }
    // B-fragments for this wave's 2 column-groups (ct = 2*odd, 2*odd+1):
    // even wave can use its own Bf regs; odd wave reads partner slab.
    bf16x8 Bw[2][2];
    #pragma unroll
    for (int ctl = 0; ctl < 2; ++ctl) {
        int ct = 2 * odd + ctl;
        if (!odd) {
            Bw[0][ctl] = Bf[0][ct];
            Bw[1][ctl] = Bf[1][ct];
        } else {
            int col = 16*ct + c;
            #pragma unroll
            for (int kt = 0; kt < 2; ++kt) {
                uint2 qa = *(const uint2*)&rlB[col * 68 + 32*kt + 4*gq];
                uint2 qb = *(const uint2*)&rlB[col * 68 + 32*kt + 16 + 4*gq];
                uint4 q; q.x = qa.x; q.y = qa.y; q.z = qb.x; q.w = qb.y;
                Bw[kt][ctl] = __builtin_bit_cast(bf16x8, q);
            }
        }
    }

    f32x4 Wt[2][4];
    float wmx = 1e-30f;
    #pragma unroll
    for (int ctl = 0; ctl < 2; ++ctl) {
        #pragma unroll
        for (int tr = 0; tr < 4; ++tr) {
            f32x4 z = mfma_init(Af[tr][0], Bw[0][ctl], zero4);
            mfma_acc(z, Af[tr][1], Bw[1][ctl]);
            Wt[ctl][tr] = z;
        }
    }
    asm volatile("s_nop 7\ns_nop 7");
    #pragma unroll
    for (int ctl = 0; ctl < 2; ++ctl)
      #pragma unroll
      for (int tr = 0; tr < 4; ++tr)
          wmx = fmaxf(wmx, fmaxf(fmaxf(Wt[ctl][tr][0], Wt[ctl][tr][1]),
                                 fmaxf(Wt[ctl][tr][2], Wt[ctl][tr][3])));
    #pragma unroll
    for (int o = 32; o > 0; o >>= 1)
        wmx = fmaxf(wmx, __shfl_xor(wmx, o));
    if (lane == 0) mx_sh[wid] = wmx;
    __syncthreads();   // also: everyone done reading slabs 2p, 2p+1

    float pmx = fmaxf(fmaxf(mx_sh[2*p], mx_sh[2*p + 1]), 1e-30f);
    int   e   = ((__float_as_int(pmx) >> 23) & 0xFF) - 127;
    float sc  = __int_as_float((unsigned)(127 - e) << 23);

    // write scaled W (bf16, col-major, C-layout rows 16tr+4gq) into slab 2p
    unsigned short* rw = relay[2*p];
    #pragma unroll
    for (int ctl = 0; ctl < 2; ++ctl) {
        int col = 16 * (2 * odd + ctl) + c;
        #pragma unroll
        for (int tr = 0; tr < 4; ++tr) {
            f32x4 v = Wt[ctl][tr] * sc;
            uint2 wv; wv.x = cvtpk_bf16(v[0], v[1]);
            wv.y = cvtpk_bf16(v[2], v[3]);
            *(uint2*)&rw[col * 68 + 16*tr + 4*gq] = wv;
        }
    }
    __syncthreads();

    if (!odd) {   // even wave stores full W row-major + Ks
        const int pair = q4 * 2 + p;
        unsigned short* zo = Zout + ((size_t)(b * 16 + pair)) * 64 * 64;
        #pragma unroll
        for (int q8 = 0; q8 < 8; ++q8) {
            unsigned dw[4];
            #pragma unroll
            for (int d = 0; d < 4; ++d) {
                unsigned lo = rw[(8*q8 + 2*d    ) * 68 + lane];
                unsigned hi = rw[(8*q8 + 2*d + 1) * 68 + lane];
                dw[d] = lo | (hi << 16);
            }
            uint4 wv; wv.x = dw[0]; wv.y = dw[1]; wv.z = dw[2]; wv.w = dw[3];
            *(uint4*)(zo + (size_t)lane * 64 + 8*q8) = wv;
        }
        if (lane == 0)
            Kout[b * 16 + pair] = kt_sh[2*p] + kt_sh[2*p + 1] + e;
    }
}

// ============================================================================
// Phase 2 (r13-validated, G=16): v <- Z_g v; exact pow2 normalizer from
// lane-1's exponent; esum folded at the end.
// ============================================================================
template<int GG>
__global__ __launch_bounds__(64, 1)
void crf_apply(const float* __restrict__ features,
               const int*   __restrict__ labels,
               const float* __restrict__ mask,
               const float* __restrict__ transitions,
               const unsigned short* __restrict__ Zmat,
               const int*   __restrict__ Kscale,
               float*       __restrict__ res)
{
    __shared__ float trans_lds[T * T];
    __shared__ float bcast[2][T];
    const int lane = threadIdx.x;
    const int b = blockIdx.x;

    for (int i = 0; i < T; ++i)
        trans_lds[i * T + lane] = transitions[i * T + lane];
    __syncthreads();

    const float* fb = features + (size_t)b * S * T;
    const int*   lb = labels + (size_t)b * S;
    const float* mb = mask + (size_t)b * S;

    float gold = 0.f;
    #pragma unroll
    for (int ch = 0; ch < S / T; ++ch) {
        int tt = ch * T + lane;
        int tm1 = tt > 0 ? tt - 1 : 0;
        int la = lb[tt], lp = lb[tm1];
        float mt = mb[tt], mp = mb[tm1];
        float em_g = fb[(size_t)tt * T + la];
        float tr_g = trans_lds[lp * T + la];
        gold += em_g * mt + ((tt > 0) ? tr_g * (mp * mt) : 0.f);
    }

    float a0 = fb[lane];
    float A0 = a0;
    #pragma unroll
    for (int o = 32; o > 0; o >>= 1) A0 = fmaxf(A0, __shfl_xor(A0, o));
    float v = __expf(a0 - A0);

    int esum = 0;

    const unsigned short* zb = Zmat + ((size_t)b * GG) * 64 * 64 + (size_t)lane * 64;
    uint4 cur[8], nxt[8];
    #pragma unroll
    for (int i = 0; i < 8; ++i) cur[i] = ((const uint4*)zb)[i];

    for (int g = 0; g < GG; ++g) {
        if (g + 1 < GG) {
            const uint4* zn = (const uint4*)(zb + (size_t)(g + 1) * 64 * 64);
            #pragma unroll
            for (int i = 0; i < 8; ++i) nxt[i] = zn[i];
        }
        const int buf = g & 1;
        bcast[buf][lane] = v;
        asm volatile("s_waitcnt lgkmcnt(0)" ::: "memory");
        f32x4 vb[16];
        #pragma unroll
        for (int q = 0; q < 16; ++q) vb[q] = ((const f32x4*)bcast[buf])[q];

        float ac0 = 0.f, ac1 = 0.f, ac2 = 0.f, ac3 = 0.f;
        #pragma unroll
        for (int i = 0; i < 8; ++i) {
            unsigned zz[4] = {cur[i].x, cur[i].y, cur[i].z, cur[i].w};
            #pragma unroll
            for (int d = 0; d < 4; ++d) {
                int k = i * 8 + d * 2;
                float f0 = __int_as_float(zz[d] << 16);
                float f1 = __int_as_float(zz[d] & 0xFFFF0000u);
                if ((d & 1) == 0) { ac0 = fmaf(f0, vb[k >> 2][k & 3], ac0);
                                    ac1 = fmaf(f1, vb[(k+1) >> 2][(k+1) & 3], ac1); }
                else             { ac2 = fmaf(f0, vb[k >> 2][k & 3], ac2);
                                    ac3 = fmaf(f1, vb[(k+1) >> 2][(k+1) & 3], ac3); }
            }
        }
        float acc = (ac0 + ac1) + (ac2 + ac3);

        float a1 = fmaxf(rdlane(acc, 1), 1e-30f);
        int e = ((__float_as_int(a1) >> 23) & 0xFF) - 127;
        v = acc * __int_as_float((unsigned)(127 - e) << 23);
        esum += e + Kscale[b * GG + g];

        #pragma unroll
        for (int i = 0; i < 8; ++i) cur[i] = nxt[i];
    }

    float sum = v;
    #pragma unroll
    for (int o = 32; o > 0; o >>= 1) sum += __shfl_xor(sum, o);
    float logZ = __logf(fmaxf(sum, 1e-30f)) + A0 + (float)esum * 0.69314718056f;

    #pragma unroll
    for (int o = 32; o > 0; o >>= 1) gold += __shfl_xor(gold, o);

    if (lane == 0) res[b] = logZ - gold;
}

// ============================================================================
// Fallback: validated round-3 sequential kernel (used if ws too small)
// ============================================================================
__global__ __launch_bounds__(64, 1)
void crf_fwd_seq(const float* __restrict__ features,
                 const int*   __restrict__ labels,
                 const float* __restrict__ mask,
                 const float* __restrict__ transitions,
                 float*       __restrict__ ws)
{
    __shared__ float trans_lds[T * T];
    __shared__ __align__(16) _Float16 ea_lds[2][T];

    const int lane = threadIdx.x;
    const int b    = blockIdx.x;

    for (int i = 0; i < T; ++i)
        trans_lds[i * T + lane] = transitions[i * T + lane];
    __syncthreads();

    h2 etr[T / 2];
    #pragma unroll
    for (int k = 0; k < T / 2; ++k) {
        etr[k].x = (_Float16)__expf(trans_lds[(2 * k + 0) * T + lane]);
        etr[k].y = (_Float16)__expf(trans_lds[(2 * k + 1) * T + lane]);
    }

    const float* fb = features + (size_t)b * S * T;
    const float* mb = mask + (size_t)b * S;
    const int*   lb = labels + (size_t)b * S;

    float alpha = fb[lane];
    float gold_part = 0.f;
    float M = 0.f;

    float em_n1 = fb[1 * T + lane];
    float em_n2 = fb[2 * T + lane];
    float em_n3 = fb[3 * T + lane];

    int   lab_c = lb[lane];
    int   lab_p = lb[lane > 0 ? lane - 1 : 0];
    float m_c   = mb[lane];
    float m_p   = mb[lane > 0 ? lane - 1 : 0];

    for (int ch = 0; ch < S / T; ++ch) {
        const int base = ch * T;
        const int tt   = base + lane;

        const int   glab  = lab_c;
        const int   glabp = lab_p;
        const float gmc   = m_c;
        const float gmp   = m_p;
        const float mreg  = m_c;

        float em_g = fb[(size_t)tt * T + glab];
        float tr_g = trans_lds[glabp * T + glab];

        {
            int tn  = tt + T;  if (tn > S - 1) tn = S - 1;
            int tnp = tn - 1;  if (tnp < 0) tnp = 0;
            lab_c = lb[tn]; lab_p = lb[tnp];
            m_c   = mb[tn]; m_p   = mb[tnp];
        }

        const int i0 = (ch == 0) ? 1 : 0;
        #pragma unroll 4
        for (int i = i0; i < T; ++i) {
            const int t = base + i;
            float em = em_n1;
            em_n1 = em_n2; em_n2 = em_n3;
            int tn = t + 3; if (tn > S - 1) tn = S - 1;
            em_n3 = fb[tn * T + lane];

            float ea = __expf(alpha - M);
            ea_lds[t & 1][lane] = (_Float16)ea;
            asm volatile("s_waitcnt lgkmcnt(0)" ::: "memory");

            const uint4* ep = (const uint4*)&ea_lds[t & 1][0];
            float a0 = 0.f, a1 = 0.f, a2 = 0.f, a3 = 0.f;
            #pragma unroll
            for (int q = 0; q < 8; ++q) {
                uint4 r = ep[q];
                a0 = __builtin_amdgcn_fdot2(__builtin_bit_cast(h2, r.x), etr[4 * q + 0], a0, false);
                a1 = __builtin_amdgcn_fdot2(__builtin_bit_cast(h2, r.y), etr[4 * q + 1], a1, false);
                a2 = __builtin_amdgcn_fdot2(__builtin_bit_cast(h2, r.z), etr[4 * q + 2], a2, false);
                a3 = __builtin_amdgcn_fdot2(__builtin_bit_cast(h2, r.w), etr[4 * q + 3], a3, false);
            }
            float s = (a0 + a1) + (a2 + a3);

            float m_t = rdlane(mreg, i);
            float s1  = rdlane(s, 1);
            float em1 = rdlane(em, 1);
            float Mn  = M + __logf(s1) + em1;

            float val = M + __logf(s) + em;
            val = fmaxf(val, -1e30f);
            alpha = val * m_t + alpha * (1.f - m_t);
            M     = (m_t > 0.5f) ? Mn : M;
        }

        float valid = (tt > 0) ? 1.f : 0.f;
        gold_part += em_g * gmc + tr_g * (gmp * gmc) * valid;
    }

    float M2 = alpha;
    #pragma unroll
    for (int o = 32; o > 0; o >>= 1) M2 = fmaxf(M2, __shfl_xor(M2, o));
    float e2 = __expf(alpha - M2);
    #pragma unroll
    for (int o = 32; o > 0; o >>= 1) e2 += __shfl_xor(e2, o);
    float logZ = M2 + __logf(e2);

    #pragma unroll
    for (int o = 32; o > 0; o >>= 1) gold_part += __shfl_xor(gold_part, o);

    if (lane == 0) ws[b] = logZ - gold_part;
}

// Deterministic final mean over B=128 per-batch results.
__global__ __launch_bounds__(128)
void crf_reduce(const float* __restrict__ ws, float* __restrict__ out)
{
    const int tid = threadIdx.x;
    float v = ws[tid];
    #pragma unroll
    for (int o = 32; o > 0; o >>= 1) v += __shfl_xor(v, o);

    __shared__ float partial[2];
    if ((tid & 63) == 0) partial[tid >> 6] = v;
    __syncthreads();
    if (tid == 0) out[0] = (partial[0] + partial[1]) * (1.0f / (float)B);
}

extern "C" void kernel_launch(void* const* d_in, const int* in_sizes, int n_in,
                              void* d_out, int out_size, void* d_ws, size_t ws_size,
                              hipStream_t stream)
{
    const float* features    = (const float*)d_in[0]; // (B,S,T) f32
    const int*   labels      = (const int*)  d_in[1]; // (B,S) int
    const float* mask        = (const float*)d_in[2]; // (B,S) f32
    const float* transitions = (const float*)d_in[3]; // (T,T) f32
    float* out = (float*)d_out;

    constexpr int GOUT = 16;
    const size_t zbytes = (size_t)B * GOUT * 64 * 64 * sizeof(unsigned short); // 16 MB
    const size_t kbytes = (size_t)B * GOUT * sizeof(int);
    const size_t need   = zbytes + kbytes + (size_t)B * sizeof(float);

    if (ws_size >= need) {
        unsigned short* Zmat = (unsigned short*)d_ws;
        int*   Ks  = (int*)((char*)d_ws + zbytes);
        float* res = (float*)((char*)d_ws + zbytes + kbytes);
        crf_chunk_comb<<<dim3(B * 8), dim3(256), 0, stream>>>(features, mask, transitions, Zmat, Ks);
        crf_apply<GOUT><<<dim3(B), dim3(64), 0, stream>>>(features, labels, mask, transitions, Zmat, Ks, res);
        crf_reduce<<<dim3(1), dim3(128), 0, stream>>>(res, out);
    } else {
        float* res = (float*)d_ws;
        crf_fwd_seq<<<dim3(B), dim3(64), 0, stream>>>(features, labels, mask, transitions, res);
        crf_reduce<<<dim3(1), dim3(128), 0, stream>>>(res, out);
    }
}

// Round 16
// 69.604 us; speedup vs baseline: 1.7100x; 1.7100x over previous
//
#include <hip/hip_runtime.h>

#define B 128
#define S 512
#define T 64

typedef short bf16x8 __attribute__((ext_vector_type(8)));
typedef float f32x4 __attribute__((ext_vector_type(4)));
typedef _Float16 h2 __attribute__((ext_vector_type(2)));

__device__ __forceinline__ float rdlane(float v, int l) {
    return __int_as_float(__builtin_amdgcn_readlane(__float_as_int(v), l));
}
__device__ __forceinline__ unsigned cvtpk_bf16(float lo, float hi) {
    unsigned r;
    asm("v_cvt_pk_bf16_f32 %0, %1, %2" : "=v"(r) : "v"(lo), "v"(hi));
    return r;
}
__device__ __forceinline__ float fast_exp2(float x) {
    float r;
    asm("v_exp_f32 %0, %1" : "=v"(r) : "v"(x));
    return r;
}
// Inline-asm MFMA with VGPR accumulators (gfx950 unified file) — kills the
// compiler's AGPR allocation + v_accvgpr bounces (r15-validated correctness).
__device__ __forceinline__ f32x4 mfma_init(bf16x8 a, bf16x8 b, f32x4 c0) {
    f32x4 d;
    asm volatile("v_mfma_f32_16x16x32_bf16 %0, %1, %2, %3"
                 : "=&v"(d) : "v"(a), "v"(b), "v"(c0));
    return d;
}
__device__ __forceinline__ void mfma_acc(f32x4& c, bf16x8 a, bf16x8 b) {
    asm volatile("v_mfma_f32_16x16x32_bf16 %0, %1, %2, %0"
                 : "+v"(c) : "v"(a), "v"(b));
}
// A/B fragment k-index for mfma_f32_16x16x32_bf16, SPLIT-HALF mapping
// (validated round 6, absmax=0): e=0..3 -> k=4*gq+e ; e=4..7 -> k=16+4*gq+(e-4)
__device__ __forceinline__ int krow(int kt, int gq, int e) {
    return 32 * kt + ((e >> 2) << 4) + 4 * gq + (e & 3);
}

// ============================================================================
// Phase 1, ROUND 16 = r14's clean structure (no spill: FETCH 8.8MB) +
// r15's validated inline-asm MFMA so accumulators live in arch VGPRs.
// launch_bounds(256,3): ~170-reg budget — r11/r15 proved the spill cliff is
// between 3 and 4 waves/EU for this working set; stay at 3.
//  - static bf16 E^T A-fragments, diagonal applied C-side (r7/r14-validated)
//  - lazy lag-2 pow2 rescale, reduce every 4th step (r13/r14-validated)
//  - 4 waves/block, private relay slabs, G=16 (32 steps/chunk; 2048 waves)
// ============================================================================
template<int GG>
__global__ __launch_bounds__(256, 3)
void crf_chunk4(const float* __restrict__ features,
                const float* __restrict__ mask,
                const float* __restrict__ transitions,
                unsigned short* __restrict__ Zout,
                int* __restrict__ Kout)
{
    constexpr int CLT = S / GG;
    __shared__ unsigned short relay[4][T * 68];   // private slab per wave

    const int wid  = threadIdx.x >> 6;
    const int lane = threadIdx.x & 63;
    const int idx  = blockIdx.x * 4 + wid;
    const int b  = idx / GG;
    const int g  = idx % GG;
    const int c  = lane & 15;
    const int gq = lane >> 4;

    // ---- static A = E^T in bf16 fragments: A[i][k] = exp(W[k][i]) ----
    bf16x8 Ef[4][2];
    #pragma unroll
    for (int rt = 0; rt < 4; ++rt)
      #pragma unroll
      for (int kt = 0; kt < 2; ++kt) {
          unsigned dw[4];
          #pragma unroll
          for (int w = 0; w < 4; ++w) {
              int k0 = krow(kt, gq, 2 * w);      // even e: k(e+1) = k0+1
              float x0 = __expf(transitions[k0       * T + (c + 16*rt)]);
              float x1 = __expf(transitions[(k0 + 1) * T + (c + 16*rt)]);
              dw[w] = cvtpk_bf16(x0, x1);
          }
          uint4 q; q.x = dw[0]; q.y = dw[1]; q.z = dw[2]; q.w = dw[3];
          Ef[rt][kt] = __builtin_bit_cast(bf16x8, q);
      }

    // ---- Z init = identity, B-fragment layout (bf16 1.0 = 0x3F80) ----
    bf16x8 Bf[2][4];
    #pragma unroll
    for (int kt = 0; kt < 2; ++kt)
      #pragma unroll
      for (int ct = 0; ct < 4; ++ct)
        #pragma unroll
        for (int e = 0; e < 8; ++e)
            Bf[kt][ct][e] = (krow(kt, gq, e) == 16*ct + c) ? (short)0x3F80
                                                           : (short)0;

    const float* fb = features + (size_t)b * S * T;
    const float* mb = mask + (size_t)b * S;
    const int t0 = g * CLT + 1;
    const int t1 = (g == GG - 1) ? S : (t0 + CLT);

    const f32x4 zero4 = {0.f, 0.f, 0.f, 0.f};

    int ktot = 0;
    float zloc = 1.0f;     // local max since last reduce
    float mxr  = 1.0f;     // reduced max (consumed lag-2 at next window j==0)

    // emission/mask prefetch depth 1 (step ~1300cy >> L2 latency);
    // em rows for C-scale: float4 at row0 = 16*rt + 4*gq (C/D rows owned)
    f32x4 emP[4];
    #pragma unroll
    for (int rt = 0; rt < 4; ++rt)
        emP[rt] = *(const f32x4*)(fb + t0 * T + 16*rt + 4*gq);
    float mP = mb[t0];

    for (int w = 0; w < CLT / 4; ++w) {
        #pragma unroll
        for (int j = 0; j < 4; ++j) {
            const int t = t0 + 4 * w + j;
            const bool act = (t < t1);

            f32x4 emc[4];
            #pragma unroll
            for (int rt = 0; rt < 4; ++rt) emc[rt] = emP[rt];
            float mc = mP;
            {   // prefetch t+1
                int tn = min(t + 1, S - 1);
                #pragma unroll
                for (int rt = 0; rt < 4; ++rt)
                    emP[rt] = *(const f32x4*)(fb + tn * T + 16*rt + 4*gq);
                mP = mb[tn];
            }

            int kc = 0;
            if (j == 0) {   // consume reduce launched in window w-1 (lag-2)
                kc = ((__float_as_int(mxr) >> 23) & 0xFF) - 127;
                kc = kc < -30 ? -30 : (kc > 60 ? 60 : kc);
            }

            if (act && mc != 0.0f) {
                if (j == 0) ktot += kc;
                const float kcf = (j == 0) ? (float)kc : 0.0f;

                // d4[tr][r] = exp(em[row]) * 2^-kc  (off the MFMA chain)
                f32x4 d4[4];
                #pragma unroll
                for (int rt = 0; rt < 4; ++rt)
                    #pragma unroll
                    for (int r = 0; r < 4; ++r)
                        d4[rt][r] = fast_exp2(fmaf(emc[rt][r], 1.44269504f, -kcf));

                #pragma unroll
                for (int ct = 0; ct < 4; ++ct) {
                    f32x4 Ct[4];
                    #pragma unroll
                    for (int tr = 0; tr < 4; ++tr) {
                        f32x4 z = mfma_init(Ef[tr][0], Bf[0][ct], zero4);
                        mfma_acc(z, Ef[tr][1], Bf[1][ct]);
                        Ct[tr] = z;
                    }
                    asm volatile("s_nop 7\ns_nop 7");   // MFMA->VALU hazard
                    #pragma unroll
                    for (int tr = 0; tr < 4; ++tr) {
                        Ct[tr] *= d4[tr];               // C-side row scale
                        zloc = fmaxf(zloc, fmaxf(fmaxf(Ct[tr][0], Ct[tr][1]),
                                                 fmaxf(Ct[tr][2], Ct[tr][3])));
                    }
                    uint4 q0, q1;
                    q0.x = cvtpk_bf16(Ct[0][0], Ct[0][1]);
                    q0.y = cvtpk_bf16(Ct[0][2], Ct[0][3]);
                    q0.z = cvtpk_bf16(Ct[1][0], Ct[1][1]);
                    q0.w = cvtpk_bf16(Ct[1][2], Ct[1][3]);
                    q1.x = cvtpk_bf16(Ct[2][0], Ct[2][1]);
                    q1.y = cvtpk_bf16(Ct[2][2], Ct[2][3]);
                    q1.z = cvtpk_bf16(Ct[3][0], Ct[3][1]);
                    q1.w = cvtpk_bf16(Ct[3][2], Ct[3][3]);
                    Bf[0][ct] = __builtin_bit_cast(bf16x8, q0);
                    Bf[1][ct] = __builtin_bit_cast(bf16x8, q1);
                }
            }

            if (j == 2) {   // cross-lane reduce, consumed next window
                float mr = zloc;
                #pragma unroll
                for (int o = 32; o > 0; o >>= 1)
                    mr = fmaxf(mr, __shfl_xor(mr, o));
                mxr = mr; zloc = 1.0f;
            }
        }
    }

    // ---- ONE-TIME relayout to row-major bf16 Zout via private LDS slab ----
    unsigned short* rl = relay[wid];
    #pragma unroll
    for (int kt = 0; kt < 2; ++kt)
      #pragma unroll
      for (int ct = 0; ct < 4; ++ct) {
          uint4 q = __builtin_bit_cast(uint4, Bf[kt][ct]);
          int col = 16*ct + c;
          uint2 wa; wa.x = q.x; wa.y = q.y;     // rows 32kt+4gq+0..3
          uint2 wb; wb.x = q.z; wb.y = q.w;     // rows 32kt+16+4gq+0..3
          *(uint2*)&rl[col * 68 + 32*kt      + 4*gq] = wa;
          *(uint2*)&rl[col * 68 + 32*kt + 16 + 4*gq] = wb;
      }
    asm volatile("s_waitcnt lgkmcnt(0)" ::: "memory");

    unsigned short* zo = Zout + ((size_t)(b * GG + g)) * 64 * 64;
    #pragma unroll
    for (int q8 = 0; q8 < 8; ++q8) {
        unsigned dw[4];
        #pragma unroll
        for (int d = 0; d < 4; ++d) {
            unsigned lo = rl[(8*q8 + 2*d    ) * 68 + lane];
            unsigned hi = rl[(8*q8 + 2*d + 1) * 68 + lane];
            dw[d] = lo | (hi << 16);
        }
        uint4 wv; wv.x = dw[0]; wv.y = dw[1]; wv.z = dw[2]; wv.w = dw[3];
        *(uint4*)(zo + (size_t)lane * 64 + 8*q8) = wv;
    }
    if (lane == 0) Kout[b * GG + g] = ktot;
}

// ============================================================================
// Phase 2 (r13/r14-validated): one wave per batch, v <- Z_g v; exact pow2
// normalizer from lane-1's exponent; esum folded at the end. Depth-2 Z
// prefetch.
// ============================================================================
template<int GG>
__global__ __launch_bounds__(64, 1)
void crf_apply(const float* __restrict__ features,
               const int*   __restrict__ labels,
               const float* __restrict__ mask,
               const float* __restrict__ transitions,
               const unsigned short* __restrict__ Zmat,
               const int*   __restrict__ Kscale,
               float*       __restrict__ res)
{
    __shared__ float trans_lds[T * T];
    __shared__ float bcast[2][T];
    const int lane = threadIdx.x;
    const int b = blockIdx.x;

    for (int i = 0; i < T; ++i)
        trans_lds[i * T + lane] = transitions[i * T + lane];
    __syncthreads();

    const float* fb = features + (size_t)b * S * T;
    const int*   lb = labels + (size_t)b * S;
    const float* mb = mask + (size_t)b * S;

    // ---- gold score (lane i handles t = 64*ch + i) ----
    float gold = 0.f;
    #pragma unroll
    for (int ch = 0; ch < S / T; ++ch) {
        int tt = ch * T + lane;
        int tm1 = tt > 0 ? tt - 1 : 0;
        int la = lb[tt], lp = lb[tm1];
        float mt = mb[tt], mp = mb[tm1];
        float em_g = fb[(size_t)tt * T + la];
        float tr_g = trans_lds[lp * T + la];
        gold += em_g * mt + ((tt > 0) ? tr_g * (mp * mt) : 0.f);
    }

    // ---- v init from alpha_0 = em_0, normalized by wave max ----
    float a0 = fb[lane];
    float A0 = a0;
    #pragma unroll
    for (int o = 32; o > 0; o >>= 1) A0 = fmaxf(A0, __shfl_xor(A0, o));
    float v = __expf(a0 - A0);

    int esum = 0;

    // depth-2 prefetched Z-row loads (lane j holds row j)
    const unsigned short* zb = Zmat + ((size_t)b * GG) * 64 * 64 + (size_t)lane * 64;
    uint4 cur[8], n1[8], n2[8];
    #pragma unroll
    for (int i = 0; i < 8; ++i) cur[i] = ((const uint4*)zb)[i];
    #pragma unroll
    for (int i = 0; i < 8; ++i) n1[i] = ((const uint4*)(zb + 64 * 64))[i];
    #pragma unroll
    for (int i = 0; i < 8; ++i) n2[i] = ((const uint4*)(zb + 2 * 64 * 64))[i];

    for (int g = 0; g < GG; ++g) {
        const int buf = g & 1;
        bcast[buf][lane] = v;
        asm volatile("s_waitcnt lgkmcnt(0)" ::: "memory");
        f32x4 vb[16];
        #pragma unroll
        for (int q = 0; q < 16; ++q) vb[q] = ((const f32x4*)bcast[buf])[q];

        float ac0 = 0.f, ac1 = 0.f, ac2 = 0.f, ac3 = 0.f;
        #pragma unroll
        for (int i = 0; i < 8; ++i) {
            unsigned zz[4] = {cur[i].x, cur[i].y, cur[i].z, cur[i].w};
            #pragma unroll
            for (int d = 0; d < 4; ++d) {
                int k = i * 8 + d * 2;
                float f0 = __int_as_float(zz[d] << 16);
                float f1 = __int_as_float(zz[d] & 0xFFFF0000u);
                if ((d & 1) == 0) { ac0 = fmaf(f0, vb[k >> 2][k & 3], ac0);
                                    ac1 = fmaf(f1, vb[(k+1) >> 2][(k+1) & 3], ac1); }
                else             { ac2 = fmaf(f0, vb[k >> 2][k & 3], ac2);
                                    ac3 = fmaf(f1, vb[(k+1) >> 2][(k+1) & 3], ac3); }
            }
        }
        float acc = (ac0 + ac1) + (ac2 + ac3);

        // exact pow2 normalizer from lane 1's exponent (lane 0 is PAD -> 0)
        float a1 = fmaxf(rdlane(acc, 1), 1e-30f);
        int e = ((__float_as_int(a1) >> 23) & 0xFF) - 127;
        v = acc * __int_as_float((unsigned)(127 - e) << 23);
        esum += e + Kscale[b * GG + g];

        #pragma unroll
        for (int i = 0; i < 8; ++i) { cur[i] = n1[i]; n1[i] = n2[i]; }
        if (g + 3 < GG) {
            const uint4* zn = (const uint4*)(zb + (size_t)(g + 3) * 64 * 64);
            #pragma unroll
            for (int i = 0; i < 8; ++i) n2[i] = zn[i];
        }
    }

    float sum = v;
    #pragma unroll
    for (int o = 32; o > 0; o >>= 1) sum += __shfl_xor(sum, o);
    float logZ = __logf(fmaxf(sum, 1e-30f)) + A0 + (float)esum * 0.69314718056f;

    #pragma unroll
    for (int o = 32; o > 0; o >>= 1) gold += __shfl_xor(gold, o);

    if (lane == 0) res[b] = logZ - gold;
}

// ============================================================================
// Fallback: validated round-3 sequential kernel (used if ws too small)
// ============================================================================
__global__ __launch_bounds__(64, 1)
void crf_fwd_seq(const float* __restrict__ features,
                 const int*   __restrict__ labels,
                 const float* __restrict__ mask,
                 const float* __restrict__ transitions,
                 float*       __restrict__ ws)
{
    __shared__ float trans_lds[T * T];
    __shared__ __align__(16) _Float16 ea_lds[2][T];

    const int lane = threadIdx.x;
    const int b    = blockIdx.x;

    for (int i = 0; i < T; ++i)
        trans_lds[i * T + lane] = transitions[i * T + lane];
    __syncthreads();

    h2 etr[T / 2];
    #pragma unroll
    for (int k = 0; k < T / 2; ++k) {
        etr[k].x = (_Float16)__expf(trans_lds[(2 * k + 0) * T + lane]);
        etr[k].y = (_Float16)__expf(trans_lds[(2 * k + 1) * T + lane]);
    }

    const float* fb = features + (size_t)b * S * T;
    const float* mb = mask + (size_t)b * S;
    const int*   lb = labels + (size_t)b * S;

    float alpha = fb[lane];
    float gold_part = 0.f;
    float M = 0.f;

    float em_n1 = fb[1 * T + lane];
    float em_n2 = fb[2 * T + lane];
    float em_n3 = fb[3 * T + lane];

    int   lab_c = lb[lane];
    int   lab_p = lb[lane > 0 ? lane - 1 : 0];
    float m_c   = mb[lane];
    float m_p   = mb[lane > 0 ? lane - 1 : 0];

    for (int ch = 0; ch < S / T; ++ch) {
        const int base = ch * T;
        const int tt   = base + lane;

        const int   glab  = lab_c;
        const int   glabp = lab_p;
        const float gmc   = m_c;
        const float gmp   = m_p;
        const float mreg  = m_c;

        float em_g = fb[(size_t)tt * T + glab];
        float tr_g = trans_lds[glabp * T + glab];

        {
            int tn  = tt + T;  if (tn > S - 1) tn = S - 1;
            int tnp = tn - 1;  if (tnp < 0) tnp = 0;
            lab_c = lb[tn]; lab_p = lb[tnp];
            m_c   = mb[tn]; m_p   = mb[tnp];
        }

        const int i0 = (ch == 0) ? 1 : 0;
        #pragma unroll 4
        for (int i = i0; i < T; ++i) {
            const int t = base + i;
            float em = em_n1;
            em_n1 = em_n2; em_n2 = em_n3;
            int tn = t + 3; if (tn > S - 1) tn = S - 1;
            em_n3 = fb[tn * T + lane];

            float ea = __expf(alpha - M);
            ea_lds[t & 1][lane] = (_Float16)ea;
            asm volatile("s_waitcnt lgkmcnt(0)" ::: "memory");

            const uint4* ep = (const uint4*)&ea_lds[t & 1][0];
            float a0 = 0.f, a1 = 0.f, a2 = 0.f, a3 = 0.f;
            #pragma unroll
            for (int q = 0; q < 8; ++q) {
                uint4 r = ep[q];
                a0 = __builtin_amdgcn_fdot2(__builtin_bit_cast(h2, r.x), etr[4 * q + 0], a0, false);
                a1 = __builtin_amdgcn_fdot2(__builtin_bit_cast(h2, r.y), etr[4 * q + 1], a1, false);
                a2 = __builtin_amdgcn_fdot2(__builtin_bit_cast(h2, r.z), etr[4 * q + 2], a2, false);
                a3 = __builtin_amdgcn_fdot2(__builtin_bit_cast(h2, r.w), etr[4 * q + 3], a3, false);
            }
            float s = (a0 + a1) + (a2 + a3);

            float m_t = rdlane(mreg, i);
            float s1  = rdlane(s, 1);
            float em1 = rdlane(em, 1);
            float Mn  = M + __logf(s1) + em1;

            float val = M + __logf(s) + em;
            val = fmaxf(val, -1e30f);
            alpha = val * m_t + alpha * (1.f - m_t);
            M     = (m_t > 0.5f) ? Mn : M;
        }

        float valid = (tt > 0) ? 1.f : 0.f;
        gold_part += em_g * gmc + tr_g * (gmp * gmc) * valid;
    }

    float M2 = alpha;
    #pragma unroll
    for (int o = 32; o > 0; o >>= 1) M2 = fmaxf(M2, __shfl_xor(M2, o));
    float e2 = __expf(alpha - M2);
    #pragma unroll
    for (int o = 32; o > 0; o >>= 1) e2 += __shfl_xor(e2, o);
    float logZ = M2 + __logf(e2);

    #pragma unroll
    for (int o = 32; o > 0; o >>= 1) gold_part += __shfl_xor(gold_part, o);

    if (lane == 0) ws[b] = logZ - gold_part;
}

// Deterministic final mean over B=128 per-batch results.
__global__ __launch_bounds__(128)
void crf_reduce(const float* __restrict__ ws, float* __restrict__ out)
{
    const int tid = threadIdx.x;
    float v = ws[tid];
    #pragma unroll
    for (int o = 32; o > 0; o >>= 1) v += __shfl_xor(v, o);

    __shared__ float partial[2];
    if ((tid & 63) == 0) partial[tid >> 6] = v;
    __syncthreads();
    if (tid == 0) out[0] = (partial[0] + partial[1]) * (1.0f / (float)B);
}

extern "C" void kernel_launch(void* const* d_in, const int* in_sizes, int n_in,
                              void* d_out, int out_size, void* d_ws, size_t ws_size,
                              hipStream_t stream)
{
    const float* features    = (const float*)d_in[0]; // (B,S,T) f32
    const int*   labels      = (const int*)  d_in[1]; // (B,S) int
    const float* mask        = (const float*)d_in[2]; // (B,S) f32
    const float* transitions = (const float*)d_in[3]; // (T,T) f32
    float* out = (float*)d_out;

    constexpr int GG = 16;
    const size_t zbytes = (size_t)B * GG * 64 * 64 * sizeof(unsigned short); // 16 MB
    const size_t kbytes = (size_t)B * GG * sizeof(int);
    const size_t need   = zbytes + kbytes + (size_t)B * sizeof(float);

    if (ws_size >= need) {
        unsigned short* Zmat = (unsigned short*)d_ws;
        int*   Ks  = (int*)((char*)d_ws + zbytes);
        float* res = (float*)((char*)d_ws + zbytes + kbytes);
        crf_chunk4<GG><<<dim3(B * GG / 4), dim3(256), 0, stream>>>(features, mask, transitions, Zmat, Ks);
        crf_apply<GG><<<dim3(B), dim3(64), 0, stream>>>(features, labels, mask, transitions, Zmat, Ks, res);
        crf_reduce<<<dim3(1), dim3(128), 0, stream>>>(res, out);
    } else {
        float* res = (float*)d_ws;
        crf_fwd_seq<<<dim3(B), dim3(64), 0, stream>>>(features, labels, mask, transitions, res);
        crf_reduce<<<dim3(1), dim3(128), 0, stream>>>(res, out);
    }
}